// Round 4
// baseline (165.686 us; speedup 1.0000x reference)
//
#include <hip/hip_runtime.h>

#define BB 32
#define SS 2048
#define DD 1024

typedef float f32x4 __attribute__((ext_vector_type(4)));

#if defined(__has_builtin)
#  if __has_builtin(__builtin_amdgcn_exp2f)
#    define EXP2F(x) __builtin_amdgcn_exp2f(x)
#  endif
#  if __has_builtin(__builtin_amdgcn_rcpf)
#    define RCPF(x) __builtin_amdgcn_rcpf(x)
#  endif
#endif
#ifndef EXP2F
#  define EXP2F(x) exp2f(x)
#endif
#ifndef RCPF
#  define RCPF(x) (1.0f / (x))
#endif

#define LOG2E 1.44269504088896340736f

__device__ __forceinline__ float fast_tanh(float x) {
    x = fminf(fmaxf(x, -20.0f), 20.0f);
    float e = EXP2F(x * (2.0f * LOG2E));
    return (e - 1.0f) * RCPF(e + 1.0f);
}

__device__ __forceinline__ f32x4 ntload4(const float* p) {
    return __builtin_nontemporal_load((const f32x4*)p);
}

// ---------------- K1: dec_feature = dec_hidden @ W^T + b; zero sum ----------------
// 256 blocks x 4 columns. thread = (b, K-eighth e). W addresses shared by 32
// lanes (merged -> W read once from HBM, 4 MB); dh slice read once per thread,
// reused across the 4 columns (dh logical 32 MB, L2-served).
__global__ __launch_bounds__(256) void k_decfeat(
    const float* __restrict__ dh, const float* __restrict__ W,
    const float* __restrict__ bd, float* __restrict__ df,
    float* __restrict__ sum) {
    if (blockIdx.x == 0 && threadIdx.x < BB) sum[threadIdx.x] = 0.0f;
    int i0 = blockIdx.x * 4;
    int t = threadIdx.x;
    int b = t & 31, e = t >> 5;               // e in 0..7, K-eighth of 128 floats
    const f32x4* dhp = (const f32x4*)(dh + (size_t)b * DD + e * 128);
    f32x4 acc0 = {0,0,0,0}, acc1 = {0,0,0,0}, acc2 = {0,0,0,0}, acc3 = {0,0,0,0};
    const float* wbase = W + (size_t)i0 * DD + e * 128;
#pragma unroll 8
    for (int j = 0; j < 32; ++j) {
        f32x4 d = dhp[j];
        acc0 += (*(const f32x4*)(wbase + 0 * DD + j * 4)) * d;
        acc1 += (*(const f32x4*)(wbase + 1 * DD + j * 4)) * d;
        acc2 += (*(const f32x4*)(wbase + 2 * DD + j * 4)) * d;
        acc3 += (*(const f32x4*)(wbase + 3 * DD + j * 4)) * d;
    }
    __shared__ float red[32][8][4];
    red[b][e][0] = acc0.x + acc0.y + acc0.z + acc0.w;
    red[b][e][1] = acc1.x + acc1.y + acc1.z + acc1.w;
    red[b][e][2] = acc2.x + acc2.y + acc2.z + acc2.w;
    red[b][e][3] = acc3.x + acc3.y + acc3.z + acc3.w;
    __syncthreads();
    if (t < 128) {
        int b2 = t & 31, ic = t >> 5;
        float s = 0.0f;
#pragma unroll
        for (int k = 0; k < 8; ++k) s += red[b2][k][ic];
        df[(size_t)b2 * DD + i0 + ic] = s + bd[i0 + ic];
    }
}

// ---------------- K2: E[b,s] = exp(score); atomic partial of sum E*mask ----------------
// no max-subtraction: |score| <= ||v||_1 (~26), f32-safe; denominator cancels
// in the mask-renormalization.
__global__ __launch_bounds__(256) void k_score(
    const float* __restrict__ ef, const float* __restrict__ df,
    const float* __restrict__ cov, const float* __restrict__ v,
    const float* __restrict__ wc, const float* __restrict__ mask,
    float* __restrict__ E, float* __restrict__ sum) {
    int b  = blockIdx.x >> 8;               // 256 tiles per batch
    int s0 = (blockIdx.x & 255) * 8;
    int t  = threadIdx.x;
    float4 v4 = ((const float4*)v)[t];
    float4 w4 = ((const float4*)wc)[t];
    float4 d4 = ((const float4*)(df + (size_t)b * DD))[t];
    float part[8];
#pragma unroll
    for (int k = 0; k < 8; ++k) {
        int s = s0 + k;
        float c = cov[b * SS + s];
        f32x4 e4 = ntload4(ef + ((size_t)b * SS + s) * DD + t * 4);
        float t0 = fast_tanh(e4.x + d4.x + c * w4.x);
        float t1 = fast_tanh(e4.y + d4.y + c * w4.y);
        float t2 = fast_tanh(e4.z + d4.z + c * w4.z);
        float t3 = fast_tanh(e4.w + d4.w + c * w4.w);
        part[k] = v4.x * t0 + v4.y * t1 + v4.z * t2 + v4.w * t3;
    }
    __shared__ float red[4][8];
    __shared__ float em8[8];
    int lane = t & 63, wave = t >> 6;
#pragma unroll
    for (int k = 0; k < 8; ++k) {
        float p = part[k];
#pragma unroll
        for (int off = 32; off; off >>= 1) p += __shfl_down(p, off, 64);
        if (lane == 0) red[wave][k] = p;
    }
    __syncthreads();
    if (t < 8) {
        float sc = red[0][t] + red[1][t] + red[2][t] + red[3][t];
        float ee = EXP2F(sc * LOG2E);
        E[b * SS + s0 + t] = ee;
        em8[t] = ee * mask[b * SS + s0 + t];
    }
    __syncthreads();
    if (t == 0) {
        float s = em8[0] + em8[1] + em8[2] + em8[3]
                + em8[4] + em8[5] + em8[6] + em8[7];
        atomicAdd(sum + b, s);
    }
}

// ---------------- K4: attn/covnew writes + context partials ----------------
__global__ __launch_bounds__(256) void k_ctx_part(
    const float* __restrict__ eo, const float* __restrict__ E,
    const float* __restrict__ mask, const float* __restrict__ cov,
    const float* __restrict__ sum, float* __restrict__ attn,
    float* __restrict__ covnew, float* __restrict__ part) {
    int b = blockIdx.x >> 5, ch = blockIdx.x & 31;
    int t = threadIdx.x;
    int s0 = ch * 64;
    float invb = RCPF(sum[b]);
    __shared__ float als[64];
    if (t < 64) {
        int s = s0 + t;
        float a = E[b * SS + s] * mask[b * SS + s] * invb;
        attn[b * SS + s] = a;
        covnew[b * SS + s] = cov[b * SS + s] + a;
        als[t] = a;
    }
    __syncthreads();
    const float* base = eo + ((size_t)b * SS + s0) * DD;
    f32x4 acc = {0.f, 0.f, 0.f, 0.f};
#pragma unroll 8
    for (int k = 0; k < 64; ++k) {
        f32x4 e4 = ntload4(base + (size_t)k * DD + t * 4);
        acc += als[k] * e4;
    }
    ((f32x4*)part)[((size_t)b * 32 + ch) * 256 + t] = acc;
}

// ---------------- K5: reduce partials into context (256 blocks) ----------------
__global__ __launch_bounds__(256) void k_ctx_reduce(
    const float* __restrict__ part, float* __restrict__ ctx) {
    int b = blockIdx.x >> 3, dt = blockIdx.x & 7;
    int t = threadIdx.x;
    int slot = t & 31, grp = t >> 5;
    int f4 = dt * 32 + slot;
    const f32x4* p = (const f32x4*)part;
    f32x4 acc = {0.f, 0.f, 0.f, 0.f};
#pragma unroll
    for (int j = 0; j < 4; ++j) {
        int ch = grp + 8 * j;
        acc += p[((size_t)b * 32 + ch) * 256 + f4];
    }
    __shared__ f32x4 red[8][32];
    red[grp][slot] = acc;
    __syncthreads();
    if (t < 32) {
        f32x4 s = red[0][t];
#pragma unroll
        for (int g = 1; g < 8; ++g) s += red[g][t];
        ((f32x4*)ctx)[(size_t)b * 256 + dt * 32 + t] = s;
    }
}

extern "C" void kernel_launch(void* const* d_in, const int* in_sizes, int n_in,
                              void* d_out, int out_size, void* d_ws, size_t ws_size,
                              hipStream_t stream) {
    const float* dec_hidden  = (const float*)d_in[0];
    const float* enc_output  = (const float*)d_in[1];
    const float* enc_feature = (const float*)d_in[2];
    const float* enc_mask    = (const float*)d_in[3];
    // d_in[4] = sec_attn (unused by reference outputs)
    const float* coverage    = (const float*)d_in[5];
    const float* W_dec       = (const float*)d_in[6];
    const float* b_dec       = (const float*)d_in[7];
    const float* v           = (const float*)d_in[8];
    const float* w_cov       = (const float*)d_in[9];

    float* ctx    = (float*)d_out;                     // [B, DIM]   32768
    float* attn   = (float*)d_out + BB * DD;           // [B, S]     65536
    float* covnew = (float*)d_out + BB * DD + BB * SS; // [B, S]     65536

    char* ws = (char*)d_ws;
    float* df   = (float*)(ws);                        // 128 KiB
    float* E    = (float*)(ws + 131072);               // 256 KiB
    float* sum  = (float*)(ws + 393216);               // 128 B
    float* part = (float*)(ws + 394240);               // 4 MiB

    k_decfeat   <<<256,   256, 0, stream>>>(dec_hidden, W_dec, b_dec, df, sum);
    k_score     <<<8192,  256, 0, stream>>>(enc_feature, df, coverage, v, w_cov,
                                            enc_mask, E, sum);
    k_ctx_part  <<<BB*32, 256, 0, stream>>>(enc_output, E, enc_mask, coverage, sum,
                                            attn, covnew, part);
    k_ctx_reduce<<<BB*8,  256, 0, stream>>>(part, ctx);
}

// Round 5
// 100.471 us; speedup vs baseline: 1.6491x; 1.6491x over previous
//
#include <hip/hip_runtime.h>

#define BB 32
#define SS 2048
#define DD 1024

typedef float f32x4 __attribute__((ext_vector_type(4)));

#if defined(__has_builtin)
#  if __has_builtin(__builtin_amdgcn_exp2f)
#    define EXP2F(x) __builtin_amdgcn_exp2f(x)
#  endif
#  if __has_builtin(__builtin_amdgcn_rcpf)
#    define RCPF(x) __builtin_amdgcn_rcpf(x)
#  endif
#endif
#ifndef EXP2F
#  define EXP2F(x) exp2f(x)
#endif
#ifndef RCPF
#  define RCPF(x) (1.0f / (x))
#endif

#define LOG2E 1.44269504088896340736f

__device__ __forceinline__ float fast_tanh(float x) {
    x = fminf(fmaxf(x, -20.0f), 20.0f);
    float e = EXP2F(x * (2.0f * LOG2E));
    return (e - 1.0f) * RCPF(e + 1.0f);
}

__device__ __forceinline__ f32x4 ntload4(const float* p) {
    return __builtin_nontemporal_load((const f32x4*)p);
}

// ---------------- K1: dec_feature = dec_hidden @ W^T + b; zero ctx ----------------
// R2-proven form: one wave per output element (b,i); 8192 blocks x 4 waves.
// Blocks 0..31 additionally zero ctx row (for K4's atomic accumulation).
__global__ __launch_bounds__(256) void k_decfeat(
    const float* __restrict__ dh, const float* __restrict__ W,
    const float* __restrict__ bd, float* __restrict__ df,
    float* __restrict__ ctx) {
    if (blockIdx.x < BB) {
        f32x4 z = {0.f, 0.f, 0.f, 0.f};
        ((f32x4*)ctx)[blockIdx.x * 256 + threadIdx.x] = z;
    }
    int wave = threadIdx.x >> 6;
    int lane = threadIdx.x & 63;
    int o = blockIdx.x * 4 + wave;          // 0 .. 32767
    int b = o >> 10, i = o & 1023;
    const float4* wrow = (const float4*)(W + (size_t)i * DD);
    const float4* drow = (const float4*)(dh + (size_t)b * DD);
    float acc = 0.0f;
#pragma unroll
    for (int r = 0; r < 4; ++r) {
        float4 w4 = wrow[lane + 64 * r];
        float4 d4 = drow[lane + 64 * r];
        acc += w4.x * d4.x + w4.y * d4.y + w4.z * d4.z + w4.w * d4.w;
    }
#pragma unroll
    for (int off = 32; off; off >>= 1) acc += __shfl_down(acc, off, 64);
    if (lane == 0) df[o] = acc + bd[i];
}

// ---------------- K2: E[b,s] = exp(v . tanh(ef + df + cov*wc)) ----------------
// R3-proven: no max-subtraction (|score| <= ||v||_1 ~ 26, f32-safe); softmax
// denominator cancels in the mask renormalization.
__global__ __launch_bounds__(256) void k_score(
    const float* __restrict__ ef, const float* __restrict__ df,
    const float* __restrict__ cov, const float* __restrict__ v,
    const float* __restrict__ wc, float* __restrict__ E) {
    int b  = blockIdx.x >> 8;               // 256 tiles per batch
    int s0 = (blockIdx.x & 255) * 8;
    int t  = threadIdx.x;
    float4 v4 = ((const float4*)v)[t];
    float4 w4 = ((const float4*)wc)[t];
    float4 d4 = ((const float4*)(df + (size_t)b * DD))[t];
    float part[8];
#pragma unroll
    for (int k = 0; k < 8; ++k) {
        int s = s0 + k;
        float c = cov[b * SS + s];
        f32x4 e4 = ntload4(ef + ((size_t)b * SS + s) * DD + t * 4);
        float t0 = fast_tanh(e4.x + d4.x + c * w4.x);
        float t1 = fast_tanh(e4.y + d4.y + c * w4.y);
        float t2 = fast_tanh(e4.z + d4.z + c * w4.z);
        float t3 = fast_tanh(e4.w + d4.w + c * w4.w);
        part[k] = v4.x * t0 + v4.y * t1 + v4.z * t2 + v4.w * t3;
    }
    __shared__ float red[4][8];
    int lane = t & 63, wave = t >> 6;
#pragma unroll
    for (int k = 0; k < 8; ++k) {
        float p = part[k];
#pragma unroll
        for (int off = 32; off; off >>= 1) p += __shfl_down(p, off, 64);
        if (lane == 0) red[wave][k] = p;
    }
    __syncthreads();
    if (t < 8) {
        float sc = red[0][t] + red[1][t] + red[2][t] + red[3][t];
        E[b * SS + s0 + t] = EXP2F(sc * LOG2E);
    }
}

// ---------------- K4: inv (redundant row-reduce) + attn/covnew + context ----------------
// block = (b, 64-row chunk). Prologue reduces the FULL E*mask row (L2-resident,
// 32x redundant) to get inv locally -> no K3 dispatch. Epilogue atomicAdds the
// chunk's context partial into ctx (spread over 2048 cache lines) -> no K5.
__global__ __launch_bounds__(256) void k_ctx_part(
    const float* __restrict__ eo, const float* __restrict__ E,
    const float* __restrict__ mask, const float* __restrict__ cov,
    float* __restrict__ attn, float* __restrict__ covnew,
    float* __restrict__ ctx) {
    int b = blockIdx.x >> 5, ch = blockIdx.x & 31;
    int t = threadIdx.x;
    int lane = t & 63, wave = t >> 6;
    // --- inv[b] ---
    float sum = 0.0f;
#pragma unroll
    for (int k = 0; k < 8; ++k) {
        int s = t + 256 * k;
        sum += E[b * SS + s] * mask[b * SS + s];
    }
#pragma unroll
    for (int off = 32; off; off >>= 1) sum += __shfl_down(sum, off, 64);
    __shared__ float red[4];
    __shared__ float invs;
    if (lane == 0) red[wave] = sum;
    __syncthreads();
    if (t == 0) invs = RCPF(red[0] + red[1] + red[2] + red[3]);
    __syncthreads();
    // --- attn/covnew for own chunk ---
    int s0 = ch * 64;
    __shared__ float als[64];
    if (t < 64) {
        int s = s0 + t;
        float a = E[b * SS + s] * mask[b * SS + s] * invs;
        attn[b * SS + s] = a;
        covnew[b * SS + s] = cov[b * SS + s] + a;
        als[t] = a;
    }
    __syncthreads();
    // --- stream enc_output chunk ---
    const float* base = eo + ((size_t)b * SS + s0) * DD;
    f32x4 acc = {0.f, 0.f, 0.f, 0.f};
#pragma unroll 8
    for (int k = 0; k < 64; ++k) {
        f32x4 e4 = ntload4(base + (size_t)k * DD + t * 4);
        acc += als[k] * e4;
    }
    float* cp = ctx + (size_t)b * DD + t * 4;
    atomicAdd(cp + 0, acc.x);
    atomicAdd(cp + 1, acc.y);
    atomicAdd(cp + 2, acc.z);
    atomicAdd(cp + 3, acc.w);
}

extern "C" void kernel_launch(void* const* d_in, const int* in_sizes, int n_in,
                              void* d_out, int out_size, void* d_ws, size_t ws_size,
                              hipStream_t stream) {
    const float* dec_hidden  = (const float*)d_in[0];
    const float* enc_output  = (const float*)d_in[1];
    const float* enc_feature = (const float*)d_in[2];
    const float* enc_mask    = (const float*)d_in[3];
    // d_in[4] = sec_attn (unused by reference outputs)
    const float* coverage    = (const float*)d_in[5];
    const float* W_dec       = (const float*)d_in[6];
    const float* b_dec       = (const float*)d_in[7];
    const float* v           = (const float*)d_in[8];
    const float* w_cov       = (const float*)d_in[9];

    float* ctx    = (float*)d_out;                     // [B, DIM]   32768
    float* attn   = (float*)d_out + BB * DD;           // [B, S]     65536
    float* covnew = (float*)d_out + BB * DD + BB * SS; // [B, S]     65536

    char* ws = (char*)d_ws;
    float* df = (float*)(ws);                          // 128 KiB
    float* E  = (float*)(ws + 131072);                 // 256 KiB

    k_decfeat  <<<8192,  256, 0, stream>>>(dec_hidden, W_dec, b_dec, df, ctx);
    k_score    <<<8192,  256, 0, stream>>>(enc_feature, df, coverage, v, w_cov, E);
    k_ctx_part <<<BB*32, 256, 0, stream>>>(enc_output, E, enc_mask, coverage,
                                           attn, covnew, ctx);
}